// Round 1
// baseline (330.079 us; speedup 1.0000x reference)
//
#include <hip/hip_runtime.h>
#include <math.h>

// ---------------------------------------------------------------------------
// IrrepsToHessian: (16x0e+16x1e+16x2e)^2 -> 0e+1e+2e fully connected TP,
// CartesianTensor('ij=ij') basis change, per-config symmetrization.
//
// Decomposition:
//  init_kernel : compute the 15 real Wigner-3j tensors (alpha pre-folded) and
//                QCART into d_ws (696 floats) — exact port of the reference
//                numpy algorithm, double precision, parallelized over elems.
//  cart_kernel : one 64-thread block per row node r (= b*64+i). Phase A
//                computes t_p[v,i] = sum_u x1[u,i] W_p[u,v] once into LDS
//                (shared by the 64 edges of the row). Phase B: lane j handles
//                edge (r, j): G_p[i,j] = sum_v t_p[v,i] x2[v,j] in registers
//                (grouped by l2 to bound pressure), w3j contraction, QCART.
//                Writes unsymmetrized cart to d_out.
//  sym_kernel  : in-place symmetrization on d_out; task (i<j) or (i==j,a<d)
//                owns both partner elements -> race-free.
// ---------------------------------------------------------------------------

#define NPATH 15

__constant__ int cP_L1[NPATH]   = {0,1,2,0,1,1,1,2,2,0,2,1,1,2,2};
__constant__ int cP_L2[NPATH]   = {0,1,2,1,0,1,2,1,2,2,0,1,2,1,2};
__constant__ int cP_LO[NPATH]   = {0,0,0,1,1,1,1,1,1,2,2,2,2,2,2};
// dense w3j concat offsets, sizes (2l1+1)(2l2+1)(2lo+1): 1,9,25,9,9,27,45,45,75,25,25,45,75,75,125
__constant__ int cP_WOFF[NPATH] = {0,1,10,35,44,53,80,125,170,245,270,295,340,415,490}; // total 615
// t-row concat offsets, sizes (2l1+1): 1,3,5,1,3,3,3,5,5,1,5,3,3,5,5 -> total 51
__constant__ int cP_TOFF[NPATH] = {0,1,4,9,10,13,16,19,24,29,30,35,38,41,46};
// c (0..50) -> path, and index i within path's (2l1+1)
__constant__ int cC2P[51] = {0, 1,1,1, 2,2,2,2,2, 3, 4,4,4, 5,5,5, 6,6,6,
                             7,7,7,7,7, 8,8,8,8,8, 9, 10,10,10,10,10,
                             11,11,11, 12,12,12, 13,13,13,13,13, 14,14,14,14,14};
__constant__ int cC2I[51] = {0, 0,1,2, 0,1,2,3,4, 0, 0,1,2, 0,1,2, 0,1,2,
                             0,1,2,3,4, 0,1,2,3,4, 0, 0,1,2,3,4,
                             0,1,2, 0,1,2, 0,1,2,3,4, 0,1,2,3,4};

// ---------------------------------------------------------------------------
// init: Wigner 3j + QCART on device (double precision)
// ---------------------------------------------------------------------------
__device__ __forceinline__ double dfact(int n){
  double r = 1.0;
  for (int i = 2; i <= n; ++i) r *= (double)i;
  return r;
}

__device__ double su2_cg(int j1,int m1,int j2,int m2,int j3,int m3){
  if (m3 != m1 + m2) return 0.0;
  int vmin = -j1 + j2 + m3;
  if (-j1 + m1 > vmin) vmin = -j1 + m1;
  if (0 > vmin) vmin = 0;
  int vmax = j2 + j3 + m1;
  if (j3 - j1 + j2 < vmax) vmax = j3 - j1 + j2;
  if (j3 + m3 < vmax) vmax = j3 + m3;
  double C = sqrt((2.0*j3+1.0)*dfact(j3+j1-j2)*dfact(j3-j1+j2)*dfact(j1+j2-j3)
                  *dfact(j3+m3)*dfact(j3-m3)
                  /(dfact(j1+j2+j3+1)*dfact(j1-m1)*dfact(j1+m1)*dfact(j2-m2)*dfact(j2+m2)));
  double S = 0.0;
  for (int v = vmin; v <= vmax; ++v){
    double term = dfact(j2+j3+m1-v)*dfact(j1-m1+v)
                /(dfact(v)*dfact(j3-j1+j2-v)*dfact(j3+m3-v)*dfact(v+j1-j2-m3));
    S += ((v + j2 + m2) & 1) ? -term : term;
  }
  return C * S;
}

#define INIT_THREADS 512

__global__ __launch_bounds__(INIT_THREADS) void init_kernel(float* __restrict__ w3q){
  __shared__ double sCG[NPATH * 125];   // dense 5x5x5 per path
  __shared__ double sQre[3][5][5];
  __shared__ double sQim[3][5][5];
  __shared__ double sCr[615];
  __shared__ double sNorm[NPATH];
  const int tid = threadIdx.x;

  // q_real_to_complex for l = 0,1,2 (includes (-i)^l factor)
  if (tid < 3){
    int l = tid;
    for (int r = 0; r < 5; ++r)
      for (int c = 0; c < 5; ++c){ sQre[l][r][c] = 0.0; sQim[l][r][c] = 0.0; }
    double s = 1.0 / sqrt(2.0);
    for (int m = -l; m < 0; ++m){
      sQre[l][l+m][l-m] = s;     // 1/sqrt2 at col l+|m|
      sQim[l][l+m][l+m] = -s;    // -i/sqrt2 at col l-|m|
    }
    sQre[l][l][l] = 1.0;
    for (int m = 1; m <= l; ++m){
      double sgn = (m & 1) ? -1.0 : 1.0;
      sQre[l][l+m][l+m] = sgn * s;
      sQim[l][l+m][l-m] = sgn * s;
    }
    if (l == 1){           // multiply by -i : (a+bi) -> (b, -a)
      for (int r = 0; r < 5; ++r)
        for (int c = 0; c < 5; ++c){
          double a = sQre[l][r][c], b = sQim[l][r][c];
          sQre[l][r][c] = b; sQim[l][r][c] = -a;
        }
    } else if (l == 2){    // multiply by -1
      for (int r = 0; r < 5; ++r)
        for (int c = 0; c < 5; ++c){
          sQre[l][r][c] = -sQre[l][r][c]; sQim[l][r][c] = -sQim[l][r][c];
        }
    }
  }

  // CG tensor, dense 5x5x5 per path
  for (int t = tid; t < NPATH * 125; t += INIT_THREADS){
    int p = t / 125, idx = t - p * 125;
    int i = idx / 25, k = (idx / 5) % 5, m = idx % 5;
    int l1 = cP_L1[p], l2 = cP_L2[p], l3 = cP_LO[p];
    double val = 0.0;
    if (i < 2*l1+1 && k < 2*l2+1 && m < 2*l3+1)
      val = su2_cg(l1, i - l1, l2, k - l2, l3, m - l3);
    sCG[t] = val;
  }
  __syncthreads();

  // Cr[j,l,n] = Re( sum_{i,k,m} Q1[i,j] Q2[k,l] conj(Q3[m,n]) C[i,k,m] )
  for (int t = tid; t < NPATH * 125; t += INIT_THREADS){
    int p = t / 125, e = t - p * 125;
    int l1 = cP_L1[p], l2 = cP_L2[p], l3 = cP_LO[p];
    int d1 = 2*l1+1, d2 = 2*l2+1, d3 = 2*l3+1;
    if (e >= d1 * d2 * d3) continue;
    int j = e / (d2 * d3);
    int rem = e - j * (d2 * d3);
    int l = rem / d3, n = rem - l * d3;
    double acc = 0.0;
    for (int i = 0; i < d1; ++i)
      for (int k = 0; k < d2; ++k)
        for (int m = 0; m < d3; ++m){
          double c = sCG[p * 125 + (i*5 + k)*5 + m];
          if (c == 0.0) continue;
          double are = sQre[l1][i][j], aim = sQim[l1][i][j];
          double bre = sQre[l2][k][l], bim = sQim[l2][k][l];
          double tre = are*bre - aim*bim;
          double tim = are*bim + aim*bre;
          double cre = sQre[l3][m][n], cim = sQim[l3][m][n];
          acc += (tre*cre + tim*cim) * c;   // Re( t * conj(q3) )
        }
    sCr[cP_WOFF[p] + e] = acc;
  }
  __syncthreads();

  if (tid < NPATH){
    int p = tid;
    int sz = (2*cP_L1[p]+1) * (2*cP_L2[p]+1) * (2*cP_LO[p]+1);
    int off = cP_WOFF[p];
    double s2 = 0.0;
    for (int e = 0; e < sz; ++e){ double v = sCr[off+e]; s2 += v*v; }
    sNorm[p] = sqrt(s2);
  }
  __syncthreads();

  // write w3j with ALPHA folded in:
  // ALPHA = sqrt(2lo+1)/sqrt(FAN), FAN = {768, 1536, 1536}
  const double AL0 = 0.03608439182435161;   // 1/sqrt(768)
  const double AL1 = 0.04419417382415922;   // sqrt(3/1536)
  const double AL2 = 0.05705443310009863;   // sqrt(5/1536)
  for (int t = tid; t < NPATH * 125; t += INIT_THREADS){
    int p = t / 125, e = t - p * 125;
    int sz = (2*cP_L1[p]+1) * (2*cP_L2[p]+1) * (2*cP_LO[p]+1);
    if (e >= sz) continue;
    int lo = cP_LO[p];
    double al = (lo == 0) ? AL0 : ((lo == 1) ? AL1 : AL2);
    w3q[cP_WOFF[p] + e] = (float)(sCr[cP_WOFF[p] + e] / sNorm[p] * al);
  }
  // QCART[lm,i,j] = sqrt(2l+1) * w3j(1,1,l)[i,j,m]   (UNscaled w3j)
  for (int t = tid; t < 81; t += INIT_THREADS){
    int lm = t / 9, r = t - lm * 9;            // r = i*3 + j
    int l = (lm == 0) ? 0 : ((lm < 4) ? 1 : 2);
    int m = lm - l * l;
    int pq = (l == 0) ? 1 : ((l == 1) ? 5 : 11);  // paths (1,1,l)
    int e = r * (2*l + 1) + m;
    w3q[615 + t] = (float)(sCr[cP_WOFF[pq] + e] / sNorm[pq] * sqrt(2.0*l + 1.0));
  }
}

// ---------------------------------------------------------------------------
// main kernel: unsymmetrized cart per edge
// ---------------------------------------------------------------------------
__global__ __launch_bounds__(64) void cart_kernel(
    const float* __restrict__ feats,    // (4096, 144)
    const int*   __restrict__ layout,   // (E, 2)
    const float* __restrict__ tpw,      // (15, 16, 16)
    const float* __restrict__ w3q,      // 696 floats from init
    float*       __restrict__ out)      // (E, 9) unsymmetrized cart
{
  __shared__ float sT[16 * 51];   // t[v][c]  (c = pathwise concat of 2l1+1)
  __shared__ float sW3[615];      // alpha-scaled w3j
  __shared__ float sQC[81];
  const int tid = threadIdx.x;

  for (int o = tid; o < 696; o += 64){
    float v = w3q[o];
    if (o < 615) sW3[o] = v; else sQC[o - 615] = v;
  }

  const int e0  = blockIdx.x * 64;
  const int row = layout[2 * e0];            // uniform across block
  const float* __restrict__ x1 = feats + row * 144;

  // Phase A: t[v,c] = sum_u x1[l1][u][i] * W_p[u][v]
  for (int o = tid; o < 816; o += 64){
    int v = o / 51, c = o - v * 51;
    int p = cC2P[c], i = cC2I[c];
    int l1 = cP_L1[p];
    int st = 2*l1 + 1;
    int loff = (l1 == 0) ? 0 : ((l1 == 1) ? 16 : 64);
    const float* xb = x1 + loff + i;
    const float* w  = tpw + p * 256 + v;     // W[p][u][v], u-stride 16
    float s = 0.f;
    #pragma unroll
    for (int u = 0; u < 16; ++u) s += xb[u * st] * w[u * 16];
    sT[o] = s;
  }
  __syncthreads();

  // Phase B: lane = edge j
  const int e   = e0 + tid;
  const int col = layout[2 * e + 1];
  const float* __restrict__ x2 = feats + col * 144;

  float irr[9];
  #pragma unroll
  for (int k = 0; k < 9; ++k) irr[k] = 0.f;

  // ---- group l2 = 0 : paths 0 (0,0,0), 4 (1,0,1), 10 (2,0,2) ----
  {
    float G0 = 0.f, G4[3], G10[5];
    #pragma unroll
    for (int i = 0; i < 3; ++i) G4[i] = 0.f;
    #pragma unroll
    for (int i = 0; i < 5; ++i) G10[i] = 0.f;
    #pragma unroll
    for (int v = 0; v < 16; ++v){
      float xv = x2[v];
      const float* t = sT + v * 51;
      G0 += t[0] * xv;
      #pragma unroll
      for (int i = 0; i < 3; ++i) G4[i]  += t[10 + i] * xv;
      #pragma unroll
      for (int i = 0; i < 5; ++i) G10[i] += t[30 + i] * xv;
    }
    irr[0] += sW3[0] * G0;
    #pragma unroll
    for (int i = 0; i < 3; ++i)
      #pragma unroll
      for (int k = 0; k < 3; ++k) irr[1+k] += sW3[44 + i*3 + k] * G4[i];
    #pragma unroll
    for (int i = 0; i < 5; ++i)
      #pragma unroll
      for (int k = 0; k < 5; ++k) irr[4+k] += sW3[270 + i*5 + k] * G10[i];
  }

  // ---- group l2 = 1 : paths 1 (1,1,0), 3 (0,1,1), 5 (1,1,1), 7 (2,1,1),
  //                     11 (1,1,2), 13 (2,1,2) ----
  {
    float G1[9], G3[3], G5[9], G7[15], G11[9], G13[15];
    #pragma unroll
    for (int i = 0; i < 9;  ++i){ G1[i] = 0.f; G5[i] = 0.f; G11[i] = 0.f; }
    #pragma unroll
    for (int i = 0; i < 3;  ++i) G3[i] = 0.f;
    #pragma unroll
    for (int i = 0; i < 15; ++i){ G7[i] = 0.f; G13[i] = 0.f; }
    #pragma unroll
    for (int v = 0; v < 16; ++v){
      float xv[3];
      #pragma unroll
      for (int j = 0; j < 3; ++j) xv[j] = x2[16 + 3*v + j];
      const float* t = sT + v * 51;
      #pragma unroll
      for (int i = 0; i < 3; ++i){
        float ti = t[1 + i];
        #pragma unroll
        for (int j = 0; j < 3; ++j) G1[i*3+j] += ti * xv[j];
      }
      {
        float t3 = t[9];
        #pragma unroll
        for (int j = 0; j < 3; ++j) G3[j] += t3 * xv[j];
      }
      #pragma unroll
      for (int i = 0; i < 3; ++i){
        float ti = t[13 + i];
        #pragma unroll
        for (int j = 0; j < 3; ++j) G5[i*3+j] += ti * xv[j];
      }
      #pragma unroll
      for (int i = 0; i < 5; ++i){
        float ti = t[19 + i];
        #pragma unroll
        for (int j = 0; j < 3; ++j) G7[i*3+j] += ti * xv[j];
      }
      #pragma unroll
      for (int i = 0; i < 3; ++i){
        float ti = t[35 + i];
        #pragma unroll
        for (int j = 0; j < 3; ++j) G11[i*3+j] += ti * xv[j];
      }
      #pragma unroll
      for (int i = 0; i < 5; ++i){
        float ti = t[41 + i];
        #pragma unroll
        for (int j = 0; j < 3; ++j) G13[i*3+j] += ti * xv[j];
      }
    }
    #pragma unroll
    for (int i = 0; i < 3; ++i)
      #pragma unroll
      for (int j = 0; j < 3; ++j) irr[0] += sW3[1 + i*3 + j] * G1[i*3+j];
    #pragma unroll
    for (int j = 0; j < 3; ++j)
      #pragma unroll
      for (int k = 0; k < 3; ++k) irr[1+k] += sW3[35 + j*3 + k] * G3[j];
    #pragma unroll
    for (int i = 0; i < 3; ++i)
      #pragma unroll
      for (int j = 0; j < 3; ++j)
        #pragma unroll
        for (int k = 0; k < 3; ++k) irr[1+k] += sW3[53 + (i*3+j)*3 + k] * G5[i*3+j];
    #pragma unroll
    for (int i = 0; i < 5; ++i)
      #pragma unroll
      for (int j = 0; j < 3; ++j)
        #pragma unroll
        for (int k = 0; k < 3; ++k) irr[1+k] += sW3[125 + (i*3+j)*3 + k] * G7[i*3+j];
    #pragma unroll
    for (int i = 0; i < 3; ++i)
      #pragma unroll
      for (int j = 0; j < 3; ++j)
        #pragma unroll
        for (int k = 0; k < 5; ++k) irr[4+k] += sW3[295 + (i*3+j)*5 + k] * G11[i*3+j];
    #pragma unroll
    for (int i = 0; i < 5; ++i)
      #pragma unroll
      for (int j = 0; j < 3; ++j)
        #pragma unroll
        for (int k = 0; k < 5; ++k) irr[4+k] += sW3[415 + (i*3+j)*5 + k] * G13[i*3+j];
  }

  // ---- group l2 = 2 : paths 2 (2,2,0), 6 (1,2,1), 8 (2,2,1), 9 (0,2,2),
  //                     12 (1,2,2), 14 (2,2,2) ----
  {
    float G2[25], G6[15], G8[25], G9[5], G12[15], G14[25];
    #pragma unroll
    for (int i = 0; i < 25; ++i){ G2[i] = 0.f; G8[i] = 0.f; G14[i] = 0.f; }
    #pragma unroll
    for (int i = 0; i < 15; ++i){ G6[i] = 0.f; G12[i] = 0.f; }
    #pragma unroll
    for (int i = 0; i < 5;  ++i) G9[i] = 0.f;
    #pragma unroll
    for (int v = 0; v < 16; ++v){
      float xv[5];
      #pragma unroll
      for (int j = 0; j < 5; ++j) xv[j] = x2[64 + 5*v + j];
      const float* t = sT + v * 51;
      #pragma unroll
      for (int i = 0; i < 5; ++i){
        float ti = t[4 + i];
        #pragma unroll
        for (int j = 0; j < 5; ++j) G2[i*5+j] += ti * xv[j];
      }
      #pragma unroll
      for (int i = 0; i < 3; ++i){
        float ti = t[16 + i];
        #pragma unroll
        for (int j = 0; j < 5; ++j) G6[i*5+j] += ti * xv[j];
      }
      #pragma unroll
      for (int i = 0; i < 5; ++i){
        float ti = t[24 + i];
        #pragma unroll
        for (int j = 0; j < 5; ++j) G8[i*5+j] += ti * xv[j];
      }
      {
        float t9 = t[29];
        #pragma unroll
        for (int j = 0; j < 5; ++j) G9[j] += t9 * xv[j];
      }
      #pragma unroll
      for (int i = 0; i < 3; ++i){
        float ti = t[38 + i];
        #pragma unroll
        for (int j = 0; j < 5; ++j) G12[i*5+j] += ti * xv[j];
      }
      #pragma unroll
      for (int i = 0; i < 5; ++i){
        float ti = t[46 + i];
        #pragma unroll
        for (int j = 0; j < 5; ++j) G14[i*5+j] += ti * xv[j];
      }
    }
    #pragma unroll
    for (int i = 0; i < 5; ++i)
      #pragma unroll
      for (int j = 0; j < 5; ++j) irr[0] += sW3[10 + i*5 + j] * G2[i*5+j];
    #pragma unroll
    for (int i = 0; i < 3; ++i)
      #pragma unroll
      for (int j = 0; j < 5; ++j)
        #pragma unroll
        for (int k = 0; k < 3; ++k) irr[1+k] += sW3[80 + (i*5+j)*3 + k] * G6[i*5+j];
    #pragma unroll
    for (int i = 0; i < 5; ++i)
      #pragma unroll
      for (int j = 0; j < 5; ++j)
        #pragma unroll
        for (int k = 0; k < 3; ++k) irr[1+k] += sW3[170 + (i*5+j)*3 + k] * G8[i*5+j];
    #pragma unroll
    for (int j = 0; j < 5; ++j)
      #pragma unroll
      for (int k = 0; k < 5; ++k) irr[4+k] += sW3[245 + j*5 + k] * G9[j];
    #pragma unroll
    for (int i = 0; i < 3; ++i)
      #pragma unroll
      for (int j = 0; j < 5; ++j)
        #pragma unroll
        for (int k = 0; k < 5; ++k) irr[4+k] += sW3[340 + (i*5+j)*5 + k] * G12[i*5+j];
    #pragma unroll
    for (int i = 0; i < 5; ++i)
      #pragma unroll
      for (int j = 0; j < 5; ++j)
        #pragma unroll
        for (int k = 0; k < 5; ++k) irr[4+k] += sW3[490 + (i*5+j)*5 + k] * G14[i*5+j];
  }

  // cart[i*3+j] = sum_k irr[k] * QCART[k][i][j]
  float* op = out + (size_t)e * 9;
  #pragma unroll
  for (int a = 0; a < 9; ++a){
    float s = 0.f;
    #pragma unroll
    for (int k = 0; k < 9; ++k) s += irr[k] * sQC[k*9 + a];
    op[a] = s;
  }
}

// ---------------------------------------------------------------------------
// in-place symmetrization: out[b,i,j,a,d] = 0.5*(c[b,i,j,a,d] + c[b,j,i,d,a])
// Task (i<j, any a,d) or (i==j, a<d) owns both elements -> exactly-once,
// race-free. Diagonal a==d, i==j is already correct (avg with itself).
// ---------------------------------------------------------------------------
__global__ __launch_bounds__(256) void sym_kernel(float* __restrict__ out, int total){
  int o = blockIdx.x * 256 + threadIdx.x;
  if (o >= total) return;
  int e = o / 9;
  int r = o - e * 9;
  int a = r / 3, d = r - a * 3;
  int i = (e >> 6) & 63;
  int j = e & 63;
  bool active = (i < j) || (i == j && a < d);
  if (!active) return;
  int e2 = (e & ~4095) | (j << 6) | i;
  int o2 = e2 * 9 + d * 3 + a;
  float v = 0.5f * (out[o] + out[o2]);
  out[o]  = v;
  out[o2] = v;
}

// ---------------------------------------------------------------------------
extern "C" void kernel_launch(void* const* d_in, const int* in_sizes, int n_in,
                              void* d_out, int out_size, void* d_ws, size_t ws_size,
                              hipStream_t stream) {
  const float* feats  = (const float*)d_in[0];   // (4096, 144) f32
  const int*   layout = (const int*)  d_in[1];   // (E, 2) i32
  const float* tpw    = (const float*)d_in[2];   // (15, 16, 16) f32
  float* out = (float*)d_out;
  float* w3q = (float*)d_ws;                     // 696 floats scratch

  const int E = in_sizes[1] / 2;                 // 262144

  init_kernel<<<1, INIT_THREADS, 0, stream>>>(w3q);
  cart_kernel<<<E / 64, 64, 0, stream>>>(feats, layout, tpw, w3q, out);
  sym_kernel<<<(E * 9) / 256, 256, 0, stream>>>(out, E * 9);
}

// Round 2
// 244.388 us; speedup vs baseline: 1.3506x; 1.3506x over previous
//
#include <hip/hip_runtime.h>
#include <math.h>

// ---------------------------------------------------------------------------
// IrrepsToHessian, round 2.
//
// R1 post-mortem: cart_kernel hit the 256-VGPR cap and spilled ~35 MB to
// scratch (WRITE_SIZE 44.5 MB vs 9.4 MB ideal), VALUBusy 1.25% -> latency
// bound. Fix: algebraic refactor. All row-dependent work is folded into a
// per-row matrix Mq[144][9]:
//     cart[e][a] = sum_c x2feat[col(e)][c] * Mq[row(e)][c][a]
//     Mq[c][a]   = sum_{p:l2} sum_i t_p[v(c),i] * wq_p[i, j(c), a]
//     wq_p[i,j,a]= alpha_lo * sum_m w3j_p[i,j,m] * QCART[lo^2+m][a]
// Phase B per lane = 144x9 matvec -> 9 accumulators, no spills.
//
// Path A (ws big enough): mq_kernel writes Mq to global scratch; cart_smem
//   reads it via wave-uniform pointer (compiler -> s_load, SGPR-operand FMA).
// Path B (fallback):      fused kernel keeps Mq in LDS (broadcast reads).
// ---------------------------------------------------------------------------

#define NPATH 15

__constant__ int cP_L1[NPATH]   = {0,1,2,0,1,1,1,2,2,0,2,1,1,2,2};
__constant__ int cP_L2[NPATH]   = {0,1,2,1,0,1,2,1,2,2,0,1,2,1,2};
__constant__ int cP_LO[NPATH]   = {0,0,0,1,1,1,1,1,1,2,2,2,2,2,2};
// dense w3j concat offsets, sizes (2l1+1)(2l2+1)(2lo+1)
__constant__ int cP_WOFF[NPATH] = {0,1,10,35,44,53,80,125,170,245,270,295,340,415,490}; // total 615
// t-row concat offsets, sizes (2l1+1) -> total 51
__constant__ int cP_TOFF[NPATH] = {0,1,4,9,10,13,16,19,24,29,30,35,38,41,46};
// c (0..50) -> path, and index i within path's (2l1+1)
__constant__ int cC2P[51] = {0, 1,1,1, 2,2,2,2,2, 3, 4,4,4, 5,5,5, 6,6,6,
                             7,7,7,7,7, 8,8,8,8,8, 9, 10,10,10,10,10,
                             11,11,11, 12,12,12, 13,13,13,13,13, 14,14,14,14,14};
__constant__ int cC2I[51] = {0, 0,1,2, 0,1,2,3,4, 0, 0,1,2, 0,1,2, 0,1,2,
                             0,1,2,3,4, 0,1,2,3,4, 0, 0,1,2,3,4,
                             0,1,2, 0,1,2, 0,1,2,3,4, 0,1,2,3,4};

// wq layout: per path p, (i*d2 + j)*9 + a at offset WQ2OFF[p]; total 1611 floats
// WQ2OFF = 9 * cumsum(d1*d2)
#define WQ_TOTAL 1611
#define WQ_REGION 2048   // floats reserved at start of ws for wq
#define MQ_STRIDE 1296   // floats per row (144*9)

// ---------------------------------------------------------------------------
// init: Wigner 3j -> wq (alpha + QCART folded) on device, double precision
// ---------------------------------------------------------------------------
__device__ __forceinline__ double dfact(int n){
  double r = 1.0;
  for (int i = 2; i <= n; ++i) r *= (double)i;
  return r;
}

__device__ double su2_cg(int j1,int m1,int j2,int m2,int j3,int m3){
  if (m3 != m1 + m2) return 0.0;
  int vmin = -j1 + j2 + m3;
  if (-j1 + m1 > vmin) vmin = -j1 + m1;
  if (0 > vmin) vmin = 0;
  int vmax = j2 + j3 + m1;
  if (j3 - j1 + j2 < vmax) vmax = j3 - j1 + j2;
  if (j3 + m3 < vmax) vmax = j3 + m3;
  double C = sqrt((2.0*j3+1.0)*dfact(j3+j1-j2)*dfact(j3-j1+j2)*dfact(j1+j2-j3)
                  *dfact(j3+m3)*dfact(j3-m3)
                  /(dfact(j1+j2+j3+1)*dfact(j1-m1)*dfact(j1+m1)*dfact(j2-m2)*dfact(j2+m2)));
  double S = 0.0;
  for (int v = vmin; v <= vmax; ++v){
    double term = dfact(j2+j3+m1-v)*dfact(j1-m1+v)
                /(dfact(v)*dfact(j3-j1+j2-v)*dfact(j3+m3-v)*dfact(v+j1-j2-m3));
    S += ((v + j2 + m2) & 1) ? -term : term;
  }
  return C * S;
}

#define INIT_THREADS 512

__global__ __launch_bounds__(INIT_THREADS) void init_kernel(float* __restrict__ wq){
  __shared__ double sCG[NPATH * 125];
  __shared__ double sQre[3][5][5];
  __shared__ double sQim[3][5][5];
  __shared__ double sCr[615];
  __shared__ double sNorm[NPATH];
  __shared__ double sQCd[81];          // QCART[lm][i*3+j]
  const int tid = threadIdx.x;

  if (tid < 3){
    int l = tid;
    for (int r = 0; r < 5; ++r)
      for (int c = 0; c < 5; ++c){ sQre[l][r][c] = 0.0; sQim[l][r][c] = 0.0; }
    double s = 1.0 / sqrt(2.0);
    for (int m = -l; m < 0; ++m){
      sQre[l][l+m][l-m] = s;
      sQim[l][l+m][l+m] = -s;
    }
    sQre[l][l][l] = 1.0;
    for (int m = 1; m <= l; ++m){
      double sgn = (m & 1) ? -1.0 : 1.0;
      sQre[l][l+m][l+m] = sgn * s;
      sQim[l][l+m][l-m] = sgn * s;
    }
    if (l == 1){           // * (-i)
      for (int r = 0; r < 5; ++r)
        for (int c = 0; c < 5; ++c){
          double a = sQre[l][r][c], b = sQim[l][r][c];
          sQre[l][r][c] = b; sQim[l][r][c] = -a;
        }
    } else if (l == 2){    // * (-1)
      for (int r = 0; r < 5; ++r)
        for (int c = 0; c < 5; ++c){
          sQre[l][r][c] = -sQre[l][r][c]; sQim[l][r][c] = -sQim[l][r][c];
        }
    }
  }

  for (int t = tid; t < NPATH * 125; t += INIT_THREADS){
    int p = t / 125, idx = t - p * 125;
    int i = idx / 25, k = (idx / 5) % 5, m = idx % 5;
    int l1 = cP_L1[p], l2 = cP_L2[p], l3 = cP_LO[p];
    double val = 0.0;
    if (i < 2*l1+1 && k < 2*l2+1 && m < 2*l3+1)
      val = su2_cg(l1, i - l1, l2, k - l2, l3, m - l3);
    sCG[t] = val;
  }
  __syncthreads();

  // Cr[i,j,k] = Re( Q1^T Q2^T conj(Q3) applied to CG )
  for (int t = tid; t < NPATH * 125; t += INIT_THREADS){
    int p = t / 125, e = t - p * 125;
    int l1 = cP_L1[p], l2 = cP_L2[p], l3 = cP_LO[p];
    int d1 = 2*l1+1, d2 = 2*l2+1, d3 = 2*l3+1;
    if (e >= d1 * d2 * d3) continue;
    int j = e / (d2 * d3);
    int rem = e - j * (d2 * d3);
    int l = rem / d3, n = rem - l * d3;
    double acc = 0.0;
    for (int i = 0; i < d1; ++i)
      for (int k = 0; k < d2; ++k)
        for (int m = 0; m < d3; ++m){
          double c = sCG[p * 125 + (i*5 + k)*5 + m];
          if (c == 0.0) continue;
          double are = sQre[l1][i][j], aim = sQim[l1][i][j];
          double bre = sQre[l2][k][l], bim = sQim[l2][k][l];
          double tre = are*bre - aim*bim;
          double tim = are*bim + aim*bre;
          double cre = sQre[l3][m][n], cim = sQim[l3][m][n];
          acc += (tre*cre + tim*cim) * c;
        }
    sCr[cP_WOFF[p] + e] = acc;
  }
  __syncthreads();

  if (tid < NPATH){
    int p = tid;
    int sz = (2*cP_L1[p]+1) * (2*cP_L2[p]+1) * (2*cP_LO[p]+1);
    int off = cP_WOFF[p];
    double s2 = 0.0;
    for (int e = 0; e < sz; ++e){ double v = sCr[off+e]; s2 += v*v; }
    sNorm[p] = sqrt(s2);
  }
  __syncthreads();

  // QCART[lm][r] = sqrt(2l+1) * w3jn(1,1,l)[i,j,m], r = i*3+j
  for (int t = tid; t < 81; t += INIT_THREADS){
    int lm = t / 9, r = t - lm * 9;
    int l = (lm == 0) ? 0 : ((lm < 4) ? 1 : 2);
    int m = lm - l * l;
    int pq = (l == 0) ? 1 : ((l == 1) ? 5 : 11);
    int d3 = 2*l + 1;
    sQCd[lm * 9 + r] = sCr[cP_WOFF[pq] + r * d3 + m] / sNorm[pq] * sqrt(2.0*l + 1.0);
  }
  __syncthreads();

  // wq_p[i,j,a] = alpha_lo * sum_m (Cr_p[i,j,m]/norm_p) * QCART[lo^2+m][a]
  const double AL0 = 0.03608439182435161;   // 1/sqrt(768)
  const double AL1 = 0.04419417382415922;   // sqrt(3/1536)
  const double AL2 = 0.05705443310009863;   // sqrt(5/1536)
  // WQ2OFF = 9*cumsum(d1*d2)
  const int WQ2OFF[NPATH] = {0,9,90,315,342,369,450,585,720,945,990,1035,1116,1251,1386};
  for (int t = tid; t < NPATH * 225; t += INIT_THREADS){
    int p = t / 225, idx = t - p * 225;
    int i = idx / 45, j = (idx / 9) % 5, a = idx % 9;
    int d1 = 2*cP_L1[p]+1, d2 = 2*cP_L2[p]+1, d3 = 2*cP_LO[p]+1;
    if (i >= d1 || j >= d2) continue;
    int lo = cP_LO[p];
    double al = (lo == 0) ? AL0 : ((lo == 1) ? AL1 : AL2);
    double inv = 1.0 / sNorm[p];
    double acc = 0.0;
    for (int m = 0; m < d3; ++m)
      acc += sCr[cP_WOFF[p] + (i*d2 + j)*d3 + m] * inv * sQCd[(lo*lo + m)*9 + a];
    wq[WQ2OFF[p] + (i*d2 + j)*9 + a] = (float)(al * acc);
  }
}

// ---------------------------------------------------------------------------
// shared device helpers
// ---------------------------------------------------------------------------
__device__ __forceinline__ void compute_t(int tid,
                                          const float* __restrict__ sX1,
                                          const float* __restrict__ tpw,
                                          float* __restrict__ sT){
  // t[v*51 + tcol] = sum_u x1[loff + i + u*(2l1+1)] * W[p][u][v]
  for (int o = tid; o < 816; o += 64){
    int v = o / 51, c = o - v * 51;
    int p = cC2P[c], i = cC2I[c];
    int l1 = cP_L1[p];
    int st = 2*l1 + 1;
    int loff = (l1 == 0) ? 0 : ((l1 == 1) ? 16 : 64);
    const float* xb = sX1 + loff + i;
    const float* w  = tpw + p * 256 + v;
    float s = 0.f;
    #pragma unroll
    for (int u = 0; u < 16; ++u) s += xb[u * st] * w[u * 16];
    sT[o] = s;
  }
}

// accumulate one path's contribution to acc[9] for a given (v-slice tv, j)
#define ACC_PATH(TOFF_, WQ2_, D1_, D2_)                                      \
  { _Pragma("unroll")                                                        \
    for (int i = 0; i < (D1_); ++i){                                         \
      float tpv = tv[(TOFF_) + i];                                           \
      const float* wrow = wq + (WQ2_) + (i*(D2_) + j)*9;                     \
      _Pragma("unroll")                                                      \
      for (int a = 0; a < 9; ++a) acc[a] += tpv * wrow[a];                   \
    } }

__device__ __forceinline__ void mq_for_c(int c,
                                         const float* __restrict__ sT,
                                         const float* __restrict__ wq,
                                         float acc[9]){
  #pragma unroll
  for (int a = 0; a < 9; ++a) acc[a] = 0.f;
  if (c < 16){                 // l2 = 0 : paths 0,4,10
    int v = c, j = 0;
    const float* tv = sT + v * 51;
    ACC_PATH(0,   0,    1, 1)
    ACC_PATH(10,  342,  3, 1)
    ACC_PATH(30,  990,  5, 1)
  } else if (c < 64){          // l2 = 1 : paths 1,3,5,7,11,13
    int v = (c - 16) / 3, j = (c - 16) % 3;
    const float* tv = sT + v * 51;
    ACC_PATH(1,   9,    3, 3)
    ACC_PATH(9,   315,  1, 3)
    ACC_PATH(13,  369,  3, 3)
    ACC_PATH(19,  585,  5, 3)
    ACC_PATH(35,  1035, 3, 3)
    ACC_PATH(41,  1251, 5, 3)
  } else {                     // l2 = 2 : paths 2,6,8,9,12,14
    int v = (c - 64) / 5, j = (c - 64) % 5;
    const float* tv = sT + v * 51;
    ACC_PATH(4,   90,   5, 5)
    ACC_PATH(16,  450,  3, 5)
    ACC_PATH(24,  720,  5, 5)
    ACC_PATH(29,  945,  1, 5)
    ACC_PATH(38,  1116, 3, 5)
    ACC_PATH(46,  1386, 5, 5)
  }
}

// ---------------------------------------------------------------------------
// Path A, kernel 1: materialize Mq[node][144][9] to global scratch
// ---------------------------------------------------------------------------
__global__ __launch_bounds__(64) void mq_kernel(
    const float* __restrict__ feats,    // (4096, 144)
    const float* __restrict__ tpw,      // (15, 16, 16)
    const float* __restrict__ wq,       // 1611
    float*       __restrict__ mqg)      // (4096, 1296)
{
  __shared__ float sX1[144];
  __shared__ float sT[816];
  const int tid = threadIdx.x;
  const int node = blockIdx.x;
  const float* x1 = feats + (size_t)node * 144;
  for (int o = tid; o < 144; o += 64) sX1[o] = x1[o];
  __syncthreads();
  compute_t(tid, sX1, tpw, sT);
  __syncthreads();
  for (int c = tid; c < 144; c += 64){
    float acc[9];
    mq_for_c(c, sT, wq, acc);
    float* dst = mqg + (size_t)node * MQ_STRIDE + c * 9;
    #pragma unroll
    for (int a = 0; a < 9; ++a) dst[a] = acc[a];
  }
}

// ---------------------------------------------------------------------------
// Path A, kernel 2: cart[e][a] = sum_c x2[col][c] * Mq[row][c][a]
// Mq pointer is wave-uniform -> scalar loads (SGPR-operand FMAs).
// ---------------------------------------------------------------------------
__global__ __launch_bounds__(64) void cart_smem_kernel(
    const float* __restrict__ feats,
    const int*   __restrict__ layout,
    const float* __restrict__ mqg,
    float*       __restrict__ out)
{
  const int tid = threadIdx.x;
  const int r = blockIdx.x;                      // row-block (4096)
  const size_t e = (size_t)r * 64 + tid;
  const int rowNode = layout[2 * (r * 64)];      // uniform across block
  const int col = layout[2 * e + 1];
  const float* __restrict__ x2 = feats + (size_t)col * 144;
  const float* __restrict__ m  = mqg + (size_t)rowNode * MQ_STRIDE;  // uniform

  float acc[9];
  #pragma unroll
  for (int a = 0; a < 9; ++a) acc[a] = 0.f;

  for (int cc = 0; cc < 36; ++cc){
    float4 x = *(const float4*)(x2 + cc * 4);
    const float* mb = m + cc * 36;
    #pragma unroll
    for (int q = 0; q < 4; ++q){
      float xq = (q == 0) ? x.x : (q == 1) ? x.y : (q == 2) ? x.z : x.w;
      const float* mr = mb + q * 9;
      #pragma unroll
      for (int a = 0; a < 9; ++a) acc[a] += xq * mr[a];
    }
  }

  float* op = out + e * 9;
  #pragma unroll
  for (int a = 0; a < 9; ++a) op[a] = acc[a];
}

// ---------------------------------------------------------------------------
// Path B fallback: fused, Mq in LDS (padded stride 12 for b128 alignment)
// ---------------------------------------------------------------------------
__global__ __launch_bounds__(64) void cart_fused_kernel(
    const float* __restrict__ feats,
    const int*   __restrict__ layout,
    const float* __restrict__ tpw,
    const float* __restrict__ wq,
    float*       __restrict__ out)
{
  __shared__ float sX1[144];
  __shared__ float sT[816];
  __shared__ float sMq[144 * 12];
  const int tid = threadIdx.x;
  const int r = blockIdx.x;
  const size_t e0 = (size_t)r * 64;
  const int rowNode = layout[2 * e0];
  const float* x1 = feats + (size_t)rowNode * 144;
  for (int o = tid; o < 144; o += 64) sX1[o] = x1[o];
  __syncthreads();
  compute_t(tid, sX1, tpw, sT);
  __syncthreads();
  for (int c = tid; c < 144; c += 64){
    float acc[9];
    mq_for_c(c, sT, wq, acc);
    #pragma unroll
    for (int a = 0; a < 9; ++a) sMq[c * 12 + a] = acc[a];
  }
  __syncthreads();

  const size_t e = e0 + tid;
  const int col = layout[2 * e + 1];
  const float* __restrict__ x2 = feats + (size_t)col * 144;

  float acc[9];
  #pragma unroll
  for (int a = 0; a < 9; ++a) acc[a] = 0.f;

  for (int cc = 0; cc < 36; ++cc){
    float4 x = *(const float4*)(x2 + cc * 4);
    #pragma unroll
    for (int q = 0; q < 4; ++q){
      int c = cc * 4 + q;
      float xq = (q == 0) ? x.x : (q == 1) ? x.y : (q == 2) ? x.z : x.w;
      float4 m0 = *(const float4*)&sMq[c * 12];
      float4 m1 = *(const float4*)&sMq[c * 12 + 4];
      float  m8 = sMq[c * 12 + 8];
      acc[0] += xq * m0.x; acc[1] += xq * m0.y; acc[2] += xq * m0.z;
      acc[3] += xq * m0.w; acc[4] += xq * m1.x; acc[5] += xq * m1.y;
      acc[6] += xq * m1.z; acc[7] += xq * m1.w; acc[8] += xq * m8;
    }
  }

  float* op = out + e * 9;
  #pragma unroll
  for (int a = 0; a < 9; ++a) op[a] = acc[a];
}

// ---------------------------------------------------------------------------
// in-place symmetrization (verified in R1)
// ---------------------------------------------------------------------------
__global__ __launch_bounds__(256) void sym_kernel(float* __restrict__ out, int total){
  int o = blockIdx.x * 256 + threadIdx.x;
  if (o >= total) return;
  int e = o / 9;
  int r = o - e * 9;
  int a = r / 3, d = r - a * 3;
  int i = (e >> 6) & 63;
  int j = e & 63;
  bool active = (i < j) || (i == j && a < d);
  if (!active) return;
  int e2 = (e & ~4095) | (j << 6) | i;
  int o2 = e2 * 9 + d * 3 + a;
  float v = 0.5f * (out[o] + out[o2]);
  out[o]  = v;
  out[o2] = v;
}

// ---------------------------------------------------------------------------
extern "C" void kernel_launch(void* const* d_in, const int* in_sizes, int n_in,
                              void* d_out, int out_size, void* d_ws, size_t ws_size,
                              hipStream_t stream) {
  const float* feats  = (const float*)d_in[0];   // (4096, 144)
  const int*   layout = (const int*)  d_in[1];   // (E, 2)
  const float* tpw    = (const float*)d_in[2];   // (15, 16, 16)
  float* out = (float*)d_out;
  float* wq  = (float*)d_ws;                     // first WQ_REGION floats

  const int E = in_sizes[1] / 2;                 // 262144
  const int R = E / 64;                          // 4096 rows

  init_kernel<<<1, INIT_THREADS, 0, stream>>>(wq);

  const size_t need = ((size_t)WQ_REGION + (size_t)R * MQ_STRIDE) * sizeof(float);
  if (ws_size >= need){
    float* mqg = wq + WQ_REGION;
    mq_kernel<<<R, 64, 0, stream>>>(feats, tpw, wq, mqg);
    cart_smem_kernel<<<R, 64, 0, stream>>>(feats, layout, mqg, out);
  } else {
    cart_fused_kernel<<<R, 64, 0, stream>>>(feats, layout, tpw, wq, out);
  }
  sym_kernel<<<(E * 9 + 255) / 256, 256, 0, stream>>>(out, E * 9);
}

// Round 3
// 204.935 us; speedup vs baseline: 1.6107x; 1.1925x over previous
//
#include <hip/hip_runtime.h>
#include <math.h>

// ---------------------------------------------------------------------------
// IrrepsToHessian, round 3.
//
// R2 post-mortem: mq_kernel (111us) latency-bound on divergent scalar global
// loads of wq/tpw (VALUBusy 8.3%); cart_smem's Mq pointer came from a VGPR
// load -> never scalarized -> ~1440 vector loads/wave. Fix: single fused
// kernel, one wave per row-block (rows are bijective with blocks):
//   Phase A: t[k][v] from x1 (L1-broadcast loads) and tpw (coalesced 16-lane
//            runs), into LDS.
//   Phase B: Mq[c][a] = sum_k t-slice * wq; wq staged in LDS (8+1 split for
//            aligned b128); result written TRANSPOSED sMqT[a][c] (576B rows,
//            16B aligned, no padding needed).
//   Phase C: lane = edge; acc[9] over k: x2 float4 gathers (L2-resident) x
//            wave-broadcast ds_read_b128 of sMqT (same-addr = conflict-free).
// LDS 40.6KB/block -> 4 blocks/CU; grid 1024 = exactly 4/CU, no tail.
// ---------------------------------------------------------------------------

#define NPATH 15

__constant__ int cP_L1[NPATH]   = {0,1,2,0,1,1,1,2,2,0,2,1,1,2,2};
__constant__ int cP_L2[NPATH]   = {0,1,2,1,0,1,2,1,2,2,0,1,2,1,2};
__constant__ int cP_LO[NPATH]   = {0,0,0,1,1,1,1,1,1,2,2,2,2,2,2};
// dense w3j concat offsets, sizes (2l1+1)(2l2+1)(2lo+1)
__constant__ int cP_WOFF[NPATH] = {0,1,10,35,44,53,80,125,170,245,270,295,340,415,490};
// t-row concat offsets, sizes (2l1+1) -> total 51
__constant__ int cP_TOFF[NPATH] = {0,1,4,9,10,13,16,19,24,29,30,35,38,41,46};
// wq row offsets: cumsum of d1*d2 -> 189 rows total
__constant__ int cP_PROW[NPATH] = {0,1,10,35,38,41,50,65,80,105,110,115,124,139,164};
// c (0..50) -> path, and index i within path's (2l1+1)
__constant__ int cC2P[51] = {0, 1,1,1, 2,2,2,2,2, 3, 4,4,4, 5,5,5, 6,6,6,
                             7,7,7,7,7, 8,8,8,8,8, 9, 10,10,10,10,10,
                             11,11,11, 12,12,12, 13,13,13,13,13, 14,14,14,14,14};
__constant__ int cC2I[51] = {0, 0,1,2, 0,1,2,3,4, 0, 0,1,2, 0,1,2, 0,1,2,
                             0,1,2,3,4, 0,1,2,3,4, 0, 0,1,2,3,4,
                             0,1,2, 0,1,2, 0,1,2,3,4, 0,1,2,3,4};

// ws layout: [0,1512) = wq rows 0..7 (float4-aligned pairs); [1512,1701) = a=8
#define WS_B8   0
#define WS_B1   1512
#define WS_TOT  1701

// ---------------------------------------------------------------------------
// init: Wigner 3j -> wq (alpha + QCART folded), double precision, on device
// ---------------------------------------------------------------------------
__device__ __forceinline__ double dfact(int n){
  double r = 1.0;
  for (int i = 2; i <= n; ++i) r *= (double)i;
  return r;
}

__device__ double su2_cg(int j1,int m1,int j2,int m2,int j3,int m3){
  if (m3 != m1 + m2) return 0.0;
  int vmin = -j1 + j2 + m3;
  if (-j1 + m1 > vmin) vmin = -j1 + m1;
  if (0 > vmin) vmin = 0;
  int vmax = j2 + j3 + m1;
  if (j3 - j1 + j2 < vmax) vmax = j3 - j1 + j2;
  if (j3 + m3 < vmax) vmax = j3 + m3;
  double C = sqrt((2.0*j3+1.0)*dfact(j3+j1-j2)*dfact(j3-j1+j2)*dfact(j1+j2-j3)
                  *dfact(j3+m3)*dfact(j3-m3)
                  /(dfact(j1+j2+j3+1)*dfact(j1-m1)*dfact(j1+m1)*dfact(j2-m2)*dfact(j2+m2)));
  double S = 0.0;
  for (int v = vmin; v <= vmax; ++v){
    double term = dfact(j2+j3+m1-v)*dfact(j1-m1+v)
                /(dfact(v)*dfact(j3-j1+j2-v)*dfact(j3+m3-v)*dfact(v+j1-j2-m3));
    S += ((v + j2 + m2) & 1) ? -term : term;
  }
  return C * S;
}

#define INIT_THREADS 512

__global__ __launch_bounds__(INIT_THREADS) void init_kernel(float* __restrict__ ws){
  __shared__ double sCG[NPATH * 125];
  __shared__ double sQre[3][5][5];
  __shared__ double sQim[3][5][5];
  __shared__ double sCr[615];
  __shared__ double sNorm[NPATH];
  __shared__ double sQCd[81];
  const int tid = threadIdx.x;

  if (tid < 3){
    int l = tid;
    for (int r = 0; r < 5; ++r)
      for (int c = 0; c < 5; ++c){ sQre[l][r][c] = 0.0; sQim[l][r][c] = 0.0; }
    double s = 1.0 / sqrt(2.0);
    for (int m = -l; m < 0; ++m){
      sQre[l][l+m][l-m] = s;
      sQim[l][l+m][l+m] = -s;
    }
    sQre[l][l][l] = 1.0;
    for (int m = 1; m <= l; ++m){
      double sgn = (m & 1) ? -1.0 : 1.0;
      sQre[l][l+m][l+m] = sgn * s;
      sQim[l][l+m][l-m] = sgn * s;
    }
    if (l == 1){           // * (-i)
      for (int r = 0; r < 5; ++r)
        for (int c = 0; c < 5; ++c){
          double a = sQre[l][r][c], b = sQim[l][r][c];
          sQre[l][r][c] = b; sQim[l][r][c] = -a;
        }
    } else if (l == 2){    // * (-1)
      for (int r = 0; r < 5; ++r)
        for (int c = 0; c < 5; ++c){
          sQre[l][r][c] = -sQre[l][r][c]; sQim[l][r][c] = -sQim[l][r][c];
        }
    }
  }

  for (int t = tid; t < NPATH * 125; t += INIT_THREADS){
    int p = t / 125, idx = t - p * 125;
    int i = idx / 25, k = (idx / 5) % 5, m = idx % 5;
    int l1 = cP_L1[p], l2 = cP_L2[p], l3 = cP_LO[p];
    double val = 0.0;
    if (i < 2*l1+1 && k < 2*l2+1 && m < 2*l3+1)
      val = su2_cg(l1, i - l1, l2, k - l2, l3, m - l3);
    sCG[t] = val;
  }
  __syncthreads();

  for (int t = tid; t < NPATH * 125; t += INIT_THREADS){
    int p = t / 125, e = t - p * 125;
    int l1 = cP_L1[p], l2 = cP_L2[p], l3 = cP_LO[p];
    int d1 = 2*l1+1, d2 = 2*l2+1, d3 = 2*l3+1;
    if (e >= d1 * d2 * d3) continue;
    int j = e / (d2 * d3);
    int rem = e - j * (d2 * d3);
    int l = rem / d3, n = rem - l * d3;
    double acc = 0.0;
    for (int i = 0; i < d1; ++i)
      for (int k = 0; k < d2; ++k)
        for (int m = 0; m < d3; ++m){
          double c = sCG[p * 125 + (i*5 + k)*5 + m];
          if (c == 0.0) continue;
          double are = sQre[l1][i][j], aim = sQim[l1][i][j];
          double bre = sQre[l2][k][l], bim = sQim[l2][k][l];
          double tre = are*bre - aim*bim;
          double tim = are*bim + aim*bre;
          double cre = sQre[l3][m][n], cim = sQim[l3][m][n];
          acc += (tre*cre + tim*cim) * c;
        }
    sCr[cP_WOFF[p] + e] = acc;
  }
  __syncthreads();

  if (tid < NPATH){
    int p = tid;
    int sz = (2*cP_L1[p]+1) * (2*cP_L2[p]+1) * (2*cP_LO[p]+1);
    int off = cP_WOFF[p];
    double s2 = 0.0;
    for (int e = 0; e < sz; ++e){ double v = sCr[off+e]; s2 += v*v; }
    sNorm[p] = sqrt(s2);
  }
  __syncthreads();

  // QCART[lm][r] = sqrt(2l+1) * w3jn(1,1,l)[i,j,m], r = i*3+j
  for (int t = tid; t < 81; t += INIT_THREADS){
    int lm = t / 9, r = t - lm * 9;
    int l = (lm == 0) ? 0 : ((lm < 4) ? 1 : 2);
    int m = lm - l * l;
    int pq = (l == 0) ? 1 : ((l == 1) ? 5 : 11);
    int d3 = 2*l + 1;
    sQCd[lm * 9 + r] = sCr[cP_WOFF[pq] + r * d3 + m] / sNorm[pq] * sqrt(2.0*l + 1.0);
  }
  __syncthreads();

  // wq_p[i,j,a] = alpha_lo * sum_m (Cr_p[i,j,m]/norm_p) * QCART[lo^2+m][a]
  // written split: a<8 -> ws[row*8+a], a==8 -> ws[1512+row]
  const double AL0 = 0.03608439182435161;   // 1/sqrt(768)
  const double AL1 = 0.04419417382415922;   // sqrt(3/1536)
  const double AL2 = 0.05705443310009863;   // sqrt(5/1536)
  for (int t = tid; t < NPATH * 225; t += INIT_THREADS){
    int p = t / 225, idx = t - p * 225;
    int i = idx / 45, j = (idx / 9) % 5, a = idx % 9;
    int d1 = 2*cP_L1[p]+1, d2 = 2*cP_L2[p]+1, d3 = 2*cP_LO[p]+1;
    if (i >= d1 || j >= d2) continue;
    int lo = cP_LO[p];
    double al = (lo == 0) ? AL0 : ((lo == 1) ? AL1 : AL2);
    double inv = 1.0 / sNorm[p];
    double acc = 0.0;
    for (int m = 0; m < d3; ++m)
      acc += sCr[cP_WOFF[p] + (i*d2 + j)*d3 + m] * inv * sQCd[(lo*lo + m)*9 + a];
    int row = cP_PROW[p] + i*d2 + j;
    float val = (float)(al * acc);
    if (a < 8) ws[WS_B8 + row*8 + a];
    if (a < 8) ws[WS_B8 + row*8 + a] = val;
    else       ws[WS_B1 + row]       = val;
  }
}

// ---------------------------------------------------------------------------
// fused kernel: 256 threads = 4 waves, one wave per row-block of 64 edges
// ---------------------------------------------------------------------------
#define ACCP(TOFF_, PROW_, D1_)                                              \
  { _Pragma("unroll")                                                        \
    for (int i = 0; i < (D1_); ++i){                                         \
      float tv = pT[((TOFF_) + i) * 16 + v];                                 \
      int row = (PROW_) + i * D2 + j;                                        \
      const float4 m0 = *(const float4*)&sB8[row * 8];                       \
      const float4 m1 = *(const float4*)&sB8[row * 8 + 4];                   \
      const float  m8 = sB1[row];                                            \
      acc[0] += tv*m0.x; acc[1] += tv*m0.y; acc[2] += tv*m0.z;               \
      acc[3] += tv*m0.w; acc[4] += tv*m1.x; acc[5] += tv*m1.y;               \
      acc[6] += tv*m1.z; acc[7] += tv*m1.w; acc[8] += tv*m8;                 \
    } }

__global__ __launch_bounds__(256, 4) void fused_kernel(
    const float* __restrict__ feats,    // (4096, 144)
    const int*   __restrict__ layout,   // (E, 2)
    const float* __restrict__ tpw,      // (15, 16, 16)
    const float* __restrict__ ws,       // 1701 floats (wq split 8+1)
    float*       __restrict__ out)      // (E, 9) unsymmetrized cart
{
  __shared__ __align__(16) float sB8[189 * 8];      // 6048 B
  __shared__ float sB1[192];                        //  768 B
  __shared__ __align__(16) float sT[4][816];        // 13056 B  t[k][v] per wave
  __shared__ __align__(16) float sMqT[4][1296];     // 20736 B  Mq^T[a][c] per wave
                                                    // total 40608 B -> 4 blocks/CU
  const int tid  = threadIdx.x;
  const int wave = tid >> 6;
  const int lane = tid & 63;

  // stage wq into LDS (all 256 threads)
  for (int o = tid; o < 1512; o += 256) sB8[o] = ws[WS_B8 + o];
  if (tid < 189) sB1[tid] = ws[WS_B1 + tid];

  const int rw = blockIdx.x * 4 + wave;     // row-block id, 0..4095
  const int e0 = rw * 64;
  int rowNode = layout[2 * e0];             // same addr across wave -> 1 txn
  rowNode = __builtin_amdgcn_readfirstlane(rowNode);
  const float* __restrict__ x1 = feats + (size_t)rowNode * 144;

  // ---- Phase A: t[k][v] = sum_u x1[loff+i+u*st] * W[p][u][v], k=0..50 ----
  float* __restrict__ pT = sT[wave];
  {
    const int v  = lane & 15;
    const int cq = lane >> 4;
    for (int it = 0; it < 13; ++it){
      int c = cq + it * 4;
      if (c < 51){
        int p = cC2P[c], i = cC2I[c];
        int l1 = cP_L1[p];
        int st = 2*l1 + 1;
        int loff = (l1 == 0) ? 0 : ((l1 == 1) ? 16 : 64);
        const float* xb = x1 + loff + i;
        const float* wb = tpw + p * 256 + v;
        float s = 0.f;
        #pragma unroll
        for (int u = 0; u < 16; ++u) s += xb[u * st] * wb[u * 16];
        pT[c * 16 + v] = s;
      }
    }
  }

  __syncthreads();   // sB visible to all; also orders A before B

  // ---- Phase B: Mq^T[a][c] for c = lane, lane+64, lane+128 ----
  float* __restrict__ pM = sMqT[wave];
  for (int rnd = 0; rnd < 3; ++rnd){
    int c = lane + rnd * 64;
    if (c >= 144) break;
    float acc[9];
    #pragma unroll
    for (int a = 0; a < 9; ++a) acc[a] = 0.f;
    if (c < 16){                    // l2 = 0 : paths 0,4,10
      const int v = c, j = 0;
      const int D2 = 1;
      ACCP(0,  0,   1)
      ACCP(10, 38,  3)
      ACCP(30, 110, 5)
    } else if (c < 64){             // l2 = 1 : paths 1,3,5,7,11,13
      const int v = (c - 16) / 3, j = (c - 16) % 3;
      const int D2 = 3;
      ACCP(1,  1,   3)
      ACCP(9,  35,  1)
      ACCP(13, 41,  3)
      ACCP(19, 65,  5)
      ACCP(35, 115, 3)
      ACCP(41, 139, 5)
    } else {                        // l2 = 2 : paths 2,6,8,9,12,14
      const int v = (c - 64) / 5, j = (c - 64) % 5;
      const int D2 = 5;
      ACCP(4,  10,  5)
      ACCP(16, 50,  3)
      ACCP(24, 80,  5)
      ACCP(29, 105, 1)
      ACCP(38, 124, 3)
      ACCP(46, 164, 5)
    }
    #pragma unroll
    for (int a = 0; a < 9; ++a) pM[a * 144 + c] = acc[a];
  }
  // wave-local LDS ordering: DS ops from one wave complete in order; the
  // lgkmcnt the compiler inserts before the first read of pM suffices.

  // ---- Phase C: lane = edge; acc[9] = sum_c x2[c] * MqT[a][c] ----
  const size_t e = (size_t)e0 + lane;
  const int col = layout[2 * e + 1];
  const float* __restrict__ x2 = feats + (size_t)col * 144;

  float acc[9];
  #pragma unroll
  for (int a = 0; a < 9; ++a) acc[a] = 0.f;

  for (int chunk = 0; chunk < 4; ++chunk){
    float4 xr[9];
    #pragma unroll
    for (int q = 0; q < 9; ++q)
      xr[q] = *(const float4*)(x2 + chunk * 36 + q * 4);
    #pragma unroll
    for (int a = 0; a < 9; ++a){
      const float* mt = pM + a * 144 + chunk * 36;
      #pragma unroll
      for (int q = 0; q < 9; ++q){
        float4 m = *(const float4*)(mt + q * 4);   // wave-broadcast b128
        acc[a] += xr[q].x*m.x + xr[q].y*m.y + xr[q].z*m.z + xr[q].w*m.w;
      }
    }
  }

  float* op = out + e * 9;
  #pragma unroll
  for (int a = 0; a < 9; ++a) op[a] = acc[a];
}

// ---------------------------------------------------------------------------
// in-place symmetrization (verified R1/R2)
// ---------------------------------------------------------------------------
__global__ __launch_bounds__(256) void sym_kernel(float* __restrict__ out, int total){
  int o = blockIdx.x * 256 + threadIdx.x;
  if (o >= total) return;
  int e = o / 9;
  int r = o - e * 9;
  int a = r / 3, d = r - a * 3;
  int i = (e >> 6) & 63;
  int j = e & 63;
  bool active = (i < j) || (i == j && a < d);
  if (!active) return;
  int e2 = (e & ~4095) | (j << 6) | i;
  int o2 = e2 * 9 + d * 3 + a;
  float v = 0.5f * (out[o] + out[o2]);
  out[o]  = v;
  out[o2] = v;
}

// ---------------------------------------------------------------------------
extern "C" void kernel_launch(void* const* d_in, const int* in_sizes, int n_in,
                              void* d_out, int out_size, void* d_ws, size_t ws_size,
                              hipStream_t stream) {
  const float* feats  = (const float*)d_in[0];   // (4096, 144)
  const int*   layout = (const int*)  d_in[1];   // (E, 2)
  const float* tpw    = (const float*)d_in[2];   // (15, 16, 16)
  float* out = (float*)d_out;
  float* ws  = (float*)d_ws;                     // 1701 floats used

  const int E = in_sizes[1] / 2;                 // 262144
  const int R = E / 64;                          // 4096 row-blocks

  init_kernel<<<1, INIT_THREADS, 0, stream>>>(ws);
  fused_kernel<<<R / 4, 256, 0, stream>>>(feats, layout, tpw, ws, out);
  sym_kernel<<<(E * 9 + 255) / 256, 256, 0, stream>>>(out, E * 9);
}

// Round 4
// 133.886 us; speedup vs baseline: 2.4654x; 1.5307x over previous
//
#include <hip/hip_runtime.h>
#include <math.h>

// ---------------------------------------------------------------------------
// IrrepsToHessian, round 4.
//
// R3 post-mortem: (1) fused Phase C buffered xr[9] float4s -> allocator capped
// at 64 VGPR and spilled ~280MB of scratch traffic (WRITE 194MB vs 9.4MB
// ideal) -> 105us. (2) ~100us hid in the single-block init kernel (serial DP).
//
// R4: Phase C streams x2 one float4 at a time (~50 live VGPRs, no spill),
// output staged through LDS and stored as coalesced b128. init split:
//   initA: 15 blocks (one per CG path) compute normalized real Wigner-3j
//          (double), write to ws.
//   initB: 1 block assembles QCART and the alpha-folded wq table.
// ---------------------------------------------------------------------------

#define NPATH 15

__constant__ int cP_L1[NPATH]   = {0,1,2,0,1,1,1,2,2,0,2,1,1,2,2};
__constant__ int cP_L2[NPATH]   = {0,1,2,1,0,1,2,1,2,2,0,1,2,1,2};
__constant__ int cP_LO[NPATH]   = {0,0,0,1,1,1,1,1,1,2,2,2,2,2,2};
// dense w3j concat offsets, sizes (2l1+1)(2l2+1)(2lo+1) -> total 615
__constant__ int cP_WOFF[NPATH] = {0,1,10,35,44,53,80,125,170,245,270,295,340,415,490};
// wq row offsets: cumsum of d1*d2 -> 189 rows total
__constant__ int cP_PROW[NPATH] = {0,1,10,35,38,41,50,65,80,105,110,115,124,139,164};
// c (0..50) -> path, and index i within path's (2l1+1)
__constant__ int cC2P[51] = {0, 1,1,1, 2,2,2,2,2, 3, 4,4,4, 5,5,5, 6,6,6,
                             7,7,7,7,7, 8,8,8,8,8, 9, 10,10,10,10,10,
                             11,11,11, 12,12,12, 13,13,13,13,13, 14,14,14,14,14};
__constant__ int cC2I[51] = {0, 0,1,2, 0,1,2,3,4, 0, 0,1,2, 0,1,2, 0,1,2,
                             0,1,2,3,4, 0,1,2,3,4, 0, 0,1,2,3,4,
                             0,1,2, 0,1,2, 0,1,2,3,4, 0,1,2,3,4};

// ws layout (floats): [0,1512) wq a<8 rows; [1512,1701) wq a=8;
// [2048, 3278) normalized Cr as 615 doubles (8-byte aligned region).
#define WS_B8   0
#define WS_B1   1512
#define WS_CR   2048

// ---------------------------------------------------------------------------
// double-precision Wigner machinery
// ---------------------------------------------------------------------------
__device__ __forceinline__ double dfact(int n){
  double r = 1.0;
  for (int i = 2; i <= n; ++i) r *= (double)i;
  return r;
}

__device__ double su2_cg(int j1,int m1,int j2,int m2,int j3,int m3){
  if (m3 != m1 + m2) return 0.0;
  int vmin = -j1 + j2 + m3;
  if (-j1 + m1 > vmin) vmin = -j1 + m1;
  if (0 > vmin) vmin = 0;
  int vmax = j2 + j3 + m1;
  if (j3 - j1 + j2 < vmax) vmax = j3 - j1 + j2;
  if (j3 + m3 < vmax) vmax = j3 + m3;
  double C = sqrt((2.0*j3+1.0)*dfact(j3+j1-j2)*dfact(j3-j1+j2)*dfact(j1+j2-j3)
                  *dfact(j3+m3)*dfact(j3-m3)
                  /(dfact(j1+j2+j3+1)*dfact(j1-m1)*dfact(j1+m1)*dfact(j2-m2)*dfact(j2+m2)));
  double S = 0.0;
  for (int v = vmin; v <= vmax; ++v){
    double term = dfact(j2+j3+m1-v)*dfact(j1-m1+v)
                /(dfact(v)*dfact(j3-j1+j2-v)*dfact(j3+m3-v)*dfact(v+j1-j2-m3));
    S += ((v + j2 + m2) & 1) ? -term : term;
  }
  return C * S;
}

__device__ __forceinline__ void build_q(int l, double qre[5][5], double qim[5][5]){
  for (int r = 0; r < 5; ++r)
    for (int c = 0; c < 5; ++c){ qre[r][c] = 0.0; qim[r][c] = 0.0; }
  double s = 1.0 / sqrt(2.0);
  for (int m = -l; m < 0; ++m){
    qre[l+m][l-m] = s;
    qim[l+m][l+m] = -s;
  }
  qre[l][l] = 1.0;
  for (int m = 1; m <= l; ++m){
    double sgn = (m & 1) ? -1.0 : 1.0;
    qre[l+m][l+m] = sgn * s;
    qim[l+m][l-m] = sgn * s;
  }
  if (l == 1){           // * (-i)
    for (int r = 0; r < 5; ++r)
      for (int c = 0; c < 5; ++c){
        double a = qre[r][c], b = qim[r][c];
        qre[r][c] = b; qim[r][c] = -a;
      }
  } else if (l == 2){    // * (-1)
    for (int r = 0; r < 5; ++r)
      for (int c = 0; c < 5; ++c){ qre[r][c] = -qre[r][c]; qim[r][c] = -qim[r][c]; }
  }
}

// ---------------------------------------------------------------------------
// initA: one block per path; write normalized real w3j (double) to ws
// ---------------------------------------------------------------------------
__global__ __launch_bounds__(128) void initA_kernel(float* __restrict__ ws){
  __shared__ double sQre[3][5][5];
  __shared__ double sQim[3][5][5];
  __shared__ double sCG[125];
  __shared__ double sRed[128];
  const int p   = blockIdx.x;
  const int tid = threadIdx.x;
  const int l1 = cP_L1[p], l2 = cP_L2[p], l3 = cP_LO[p];
  const int d1 = 2*l1+1, d2 = 2*l2+1, d3 = 2*l3+1;

  if (tid < 3) build_q(tid, sQre[tid], sQim[tid]);

  if (tid < 125){
    int i = tid / 25, k = (tid / 5) % 5, m = tid % 5;
    double val = 0.0;
    if (i < d1 && k < d2 && m < d3)
      val = su2_cg(l1, i - l1, l2, k - l2, l3, m - l3);
    sCG[tid] = val;
  }
  __syncthreads();

  const int sz = d1 * d2 * d3;
  double acc = 0.0;
  if (tid < sz){
    int j = tid / (d2 * d3);
    int rem = tid - j * (d2 * d3);
    int l = rem / d3, n = rem - l * d3;
    for (int i = 0; i < d1; ++i)
      for (int k = 0; k < d2; ++k)
        for (int m = 0; m < d3; ++m){
          double c = sCG[(i*5 + k)*5 + m];
          if (c == 0.0) continue;
          double are = sQre[l1][i][j], aim = sQim[l1][i][j];
          double bre = sQre[l2][k][l], bim = sQim[l2][k][l];
          double tre = are*bre - aim*bim;
          double tim = are*bim + aim*bre;
          double cre = sQre[l3][m][n], cim = sQim[l3][m][n];
          acc += (tre*cre + tim*cim) * c;     // Re( q1 q2 conj(q3) * CG )
        }
  }
  sRed[tid] = acc * acc;
  __syncthreads();
  for (int s = 64; s > 0; s >>= 1){
    if (tid < s) sRed[tid] += sRed[tid + s];
    __syncthreads();
  }
  double inv = 1.0 / sqrt(sRed[0]);
  double* crg = (double*)(ws + WS_CR);
  if (tid < sz) crg[cP_WOFF[p] + tid] = acc * inv;
}

// ---------------------------------------------------------------------------
// initB: assemble QCART and alpha-folded wq from normalized Cr
// ---------------------------------------------------------------------------
__global__ __launch_bounds__(512) void initB_kernel(float* __restrict__ ws){
  __shared__ double sCr[615];
  __shared__ double sQCd[81];
  const int tid = threadIdx.x;
  const double* crg = (const double*)(ws + WS_CR);
  for (int t = tid; t < 615; t += 512) sCr[t] = crg[t];
  __syncthreads();

  // QCART[lm][r] = sqrt(2l+1) * w3jn(1,1,l)[i,j,m], r = i*3+j
  if (tid < 81){
    int lm = tid / 9, r = tid - lm * 9;
    int l = (lm == 0) ? 0 : ((lm < 4) ? 1 : 2);
    int m = lm - l * l;
    int pq = (l == 0) ? 1 : ((l == 1) ? 5 : 11);
    sQCd[lm * 9 + r] = sCr[cP_WOFF[pq] + r * (2*l + 1) + m] * sqrt(2.0*l + 1.0);
  }
  __syncthreads();

  // wq_p[i,j,a] = alpha_lo * sum_m Crn_p[i,j,m] * QCART[lo^2+m][a]
  const double AL0 = 0.03608439182435161;   // 1/sqrt(768)
  const double AL1 = 0.04419417382415922;   // sqrt(3/1536)
  const double AL2 = 0.05705443310009863;   // sqrt(5/1536)
  for (int t = tid; t < NPATH * 225; t += 512){
    int p = t / 225, idx = t - p * 225;
    int i = idx / 45, j = (idx / 9) % 5, a = idx % 9;
    int d1 = 2*cP_L1[p]+1, d2 = 2*cP_L2[p]+1, d3 = 2*cP_LO[p]+1;
    if (i >= d1 || j >= d2) continue;
    int lo = cP_LO[p];
    double al = (lo == 0) ? AL0 : ((lo == 1) ? AL1 : AL2);
    double acc = 0.0;
    for (int m = 0; m < d3; ++m)
      acc += sCr[cP_WOFF[p] + (i*d2 + j)*d3 + m] * sQCd[(lo*lo + m)*9 + a];
    int row = cP_PROW[p] + i*d2 + j;
    float val = (float)(al * acc);
    if (a < 8) ws[WS_B8 + row*8 + a] = val;
    else       ws[WS_B1 + row]       = val;
  }
}

// ---------------------------------------------------------------------------
// fused kernel: 256 threads = 4 waves, one wave per row-block of 64 edges
// ---------------------------------------------------------------------------
#define ACCP(TOFF_, PROW_, D1_)                                              \
  { _Pragma("unroll")                                                        \
    for (int i = 0; i < (D1_); ++i){                                         \
      float tv = pT[((TOFF_) + i) * 16 + v];                                 \
      int row = (PROW_) + i * D2 + j;                                        \
      const float4 m0 = *(const float4*)&sB8[row * 8];                       \
      const float4 m1 = *(const float4*)&sB8[row * 8 + 4];                   \
      const float  m8 = sB1[row];                                            \
      acc[0] += tv*m0.x; acc[1] += tv*m0.y; acc[2] += tv*m0.z;               \
      acc[3] += tv*m0.w; acc[4] += tv*m1.x; acc[5] += tv*m1.y;               \
      acc[6] += tv*m1.z; acc[7] += tv*m1.w; acc[8] += tv*m8;                 \
    } }

__global__ __launch_bounds__(256, 4) void fused_kernel(
    const float* __restrict__ feats,    // (4096, 144)
    const int*   __restrict__ layout,   // (E, 2)
    const float* __restrict__ tpw,      // (15, 16, 16)
    const float* __restrict__ ws,       // wq split 8+1
    float*       __restrict__ out)      // (E, 9) unsymmetrized cart
{
  __shared__ __align__(16) float sB8[189 * 8];      // 6048 B
  __shared__ float sB1[192];                        //  768 B
  __shared__ __align__(16) float sT[4][816];        // 13056 B  t[k][v] per wave
  __shared__ __align__(16) float sMqT[4][1296];     // 20736 B  Mq^T[a][c] per wave
                                                    // 40608 B -> 4 blocks/CU
  const int tid  = threadIdx.x;
  const int wave = tid >> 6;
  const int lane = tid & 63;

  // stage wq into LDS (all 256 threads)
  for (int o = tid; o < 1512; o += 256) sB8[o] = ws[WS_B8 + o];
  if (tid < 189) sB1[tid] = ws[WS_B1 + tid];

  const int rw = blockIdx.x * 4 + wave;     // row-block id, 0..4095
  const int e0 = rw * 64;
  int rowNode = layout[2 * e0];
  rowNode = __builtin_amdgcn_readfirstlane(rowNode);
  const float* __restrict__ x1 = feats + (size_t)rowNode * 144;

  // ---- Phase A: t[k][v] = sum_u x1[loff+i+u*st] * W[p][u][v], k=0..50 ----
  float* __restrict__ pT = sT[wave];
  {
    const int v  = lane & 15;
    const int cq = lane >> 4;
    for (int it = 0; it < 13; ++it){
      int c = cq + it * 4;
      if (c < 51){
        int p = cC2P[c], i = cC2I[c];
        int l1 = cP_L1[p];
        int st = 2*l1 + 1;
        int loff = (l1 == 0) ? 0 : ((l1 == 1) ? 16 : 64);
        const float* xb = x1 + loff + i;
        const float* wb = tpw + p * 256 + v;
        float s = 0.f;
        #pragma unroll
        for (int u = 0; u < 16; ++u) s += xb[u * st] * wb[u * 16];
        pT[c * 16 + v] = s;
      }
    }
  }

  __syncthreads();   // sB8/sB1 visible; wq staging ordered before Phase B

  // ---- Phase B: Mq^T[a][c] for c = lane, lane+64, lane+128 ----
  float* __restrict__ pM = sMqT[wave];
  for (int rnd = 0; rnd < 3; ++rnd){
    int c = lane + rnd * 64;
    if (c >= 144) break;
    float acc[9];
    #pragma unroll
    for (int a = 0; a < 9; ++a) acc[a] = 0.f;
    if (c < 16){                    // l2 = 0 : paths 0,4,10
      const int v = c, j = 0;
      const int D2 = 1;
      ACCP(0,  0,   1)
      ACCP(10, 38,  3)
      ACCP(30, 110, 5)
    } else if (c < 64){             // l2 = 1 : paths 1,3,5,7,11,13
      const int v = (c - 16) / 3, j = (c - 16) % 3;
      const int D2 = 3;
      ACCP(1,  1,   3)
      ACCP(9,  35,  1)
      ACCP(13, 41,  3)
      ACCP(19, 65,  5)
      ACCP(35, 115, 3)
      ACCP(41, 139, 5)
    } else {                        // l2 = 2 : paths 2,6,8,9,12,14
      const int v = (c - 64) / 5, j = (c - 64) % 5;
      const int D2 = 5;
      ACCP(4,  10,  5)
      ACCP(16, 50,  3)
      ACCP(24, 80,  5)
      ACCP(29, 105, 1)
      ACCP(38, 124, 3)
      ACCP(46, 164, 5)
    }
    #pragma unroll
    for (int a = 0; a < 9; ++a) pM[a * 144 + c] = acc[a];
  }
  // Phase B -> C is wave-local through LDS: DS ops complete in order per wave;
  // the compiler's lgkmcnt before first pM read suffices. No barrier.

  // ---- Phase C: lane = edge; acc[9] = sum_c x2[c] * MqT[a][c] ----
  const size_t e = (size_t)e0 + lane;
  const int col = layout[2 * e + 1];
  const float* __restrict__ x2 = feats + (size_t)col * 144;

  float acc[9];
  #pragma unroll
  for (int a = 0; a < 9; ++a) acc[a] = 0.f;

  for (int cc = 0; cc < 36; ++cc){
    const float4 x = *(const float4*)(x2 + cc * 4);
    const float* mb = pM + cc * 4;
    #pragma unroll
    for (int a = 0; a < 9; ++a){
      float4 m = *(const float4*)(mb + a * 144);   // wave-broadcast b128
      acc[a] += x.x*m.x + x.y*m.y + x.z*m.z + x.w*m.w;
    }
  }

  // ---- output: stage to LDS (reuse pT), store coalesced b128 ----
  #pragma unroll
  for (int a = 0; a < 9; ++a) pT[lane * 9 + a] = acc[a];
  float* ob = out + (size_t)e0 * 9;          // 2304B block, 16B aligned
  #pragma unroll
  for (int r = 0; r < 3; ++r){
    int idx = lane + r * 64;                 // float4 index 0..143
    if (idx < 144){
      float4 vv = *(const float4*)(pT + idx * 4);
      *(float4*)(ob + idx * 4) = vv;
    }
  }
}

// ---------------------------------------------------------------------------
// in-place symmetrization (verified R1-R3)
// ---------------------------------------------------------------------------
__global__ __launch_bounds__(256) void sym_kernel(float* __restrict__ out, int total){
  int o = blockIdx.x * 256 + threadIdx.x;
  if (o >= total) return;
  int e = o / 9;
  int r = o - e * 9;
  int a = r / 3, d = r - a * 3;
  int i = (e >> 6) & 63;
  int j = e & 63;
  bool active = (i < j) || (i == j && a < d);
  if (!active) return;
  int e2 = (e & ~4095) | (j << 6) | i;
  int o2 = e2 * 9 + d * 3 + a;
  float v = 0.5f * (out[o] + out[o2]);
  out[o]  = v;
  out[o2] = v;
}

// ---------------------------------------------------------------------------
extern "C" void kernel_launch(void* const* d_in, const int* in_sizes, int n_in,
                              void* d_out, int out_size, void* d_ws, size_t ws_size,
                              hipStream_t stream) {
  const float* feats  = (const float*)d_in[0];   // (4096, 144)
  const int*   layout = (const int*)  d_in[1];   // (E, 2)
  const float* tpw    = (const float*)d_in[2];   // (15, 16, 16)
  float* out = (float*)d_out;
  float* ws  = (float*)d_ws;

  const int E = in_sizes[1] / 2;                 // 262144
  const int R = E / 64;                          // 4096 row-blocks

  initA_kernel<<<NPATH, 128, 0, stream>>>(ws);
  initB_kernel<<<1, 512, 0, stream>>>(ws);
  fused_kernel<<<R / 4, 256, 0, stream>>>(feats, layout, tpw, ws, out);
  sym_kernel<<<(E * 9 + 255) / 256, 256, 0, stream>>>(out, E * 9);
}